// Round 17
// baseline (1678.033 us; speedup 1.0000x reference)
//
#include <hip/hip_runtime.h>
#include <hip/hip_bf16.h>
#include <math.h>

#define B_ 2
#define T_ 2048
#define D_ 1024
#define H_ 16
#define NL_ 6
#define DF_ 4096
#define HD_ 64
#define M_ (B_*T_)

typedef __bf16 bf16;
typedef __attribute__((ext_vector_type(8))) __bf16 bf16x8;
typedef __attribute__((ext_vector_type(4))) float f32x4;
typedef __attribute__((ext_vector_type(16))) float f32x16;
typedef __attribute__((ext_vector_type(4))) unsigned u32x4;

#define BAR() __builtin_amdgcn_s_barrier()
#define LGKM0() asm volatile("s_waitcnt lgkmcnt(0)" ::: "memory")
#define VMC(n) asm volatile("s_waitcnt vmcnt(" #n ")" ::: "memory")

__device__ __forceinline__ void gload_lds16(const void* g, void* l) {
    __builtin_amdgcn_global_load_lds((const __attribute__((address_space(1))) void*)g,
                                     (__attribute__((address_space(3))) void*)l, 16, 0, 0);
}

__device__ __forceinline__ unsigned pk2(float a, float b) {
    bf16 lo = (bf16)a, hb = (bf16)b;
    return (unsigned)__builtin_bit_cast(unsigned short, lo) |
           ((unsigned)__builtin_bit_cast(unsigned short, hb) << 16);
}

__device__ __forceinline__ float4 ld4bf(const bf16* p) {
    float4 o;
    o.x = (float)p[0]; o.y = (float)p[1]; o.z = (float)p[2]; o.w = (float)p[3];
    return o;
}

// ---------------- LayerNorm ----------------
template<bool OUT_BF16>
__global__ __launch_bounds__(256) void ln_kernel(const float* __restrict__ x,
        const float* __restrict__ w, const float* __restrict__ b,
        void* __restrict__ out) {
    const int row = blockIdx.x;
    const int t = threadIdx.x;
    const float4 xv = *(const float4*)(x + (long)row * D_ + t * 4);
    float s  = xv.x + xv.y + xv.z + xv.w;
    float sq = xv.x*xv.x + xv.y*xv.y + xv.z*xv.z + xv.w*xv.w;
    #pragma unroll
    for (int m = 32; m; m >>= 1) { s += __shfl_xor(s, m); sq += __shfl_xor(sq, m); }
    __shared__ float red[8];
    const int wid = t >> 6, lid = t & 63;
    if (lid == 0) { red[wid] = s; red[wid + 4] = sq; }
    __syncthreads();
    s  = red[0] + red[1] + red[2] + red[3];
    sq = red[4] + red[5] + red[6] + red[7];
    const float mu   = s * (1.0f / D_);
    const float var  = sq * (1.0f / D_) - mu * mu;
    const float rstd = rsqrtf(var + 1e-5f);
    const float4 wv = *(const float4*)(w + t * 4);
    const float4 bv = *(const float4*)(b + t * 4);
    float o0 = (xv.x - mu) * rstd * wv.x + bv.x;
    float o1 = (xv.y - mu) * rstd * wv.y + bv.y;
    float o2 = (xv.z - mu) * rstd * wv.z + bv.z;
    float o3 = (xv.w - mu) * rstd * wv.w + bv.w;
    if (OUT_BF16) {
        bf16* o = (bf16*)out + (long)row * D_ + t * 4;
        o[0] = (bf16)o0; o[1] = (bf16)o1; o[2] = (bf16)o2; o[3] = (bf16)o3;
    } else {
        float* o = (float*)out + (long)row * D_ + t * 4;
        o[0] = o0; o[1] = o1; o[2] = o2; o[3] = o3;
    }
}

// ------------- merged weight convert+transpose for one layer -------------
__global__ __launch_bounds__(256) void wconv_all(
        const float* __restrict__ Wq, const float* __restrict__ Wk,
        const float* __restrict__ Wv, const float* __restrict__ Wz,
        const float* __restrict__ Wr, const float* __restrict__ Wo,
        const float* __restrict__ W1, const float* __restrict__ W2,
        bf16* __restrict__ wt) {
    __shared__ float s[32][33];
    const int bid = blockIdx.x;
    const float* src; bf16* dst; int t, K, nlg;
    if (bid < 6144) {
        const int m = bid >> 10; t = bid & 1023; K = 1024; nlg = 5;
        switch (m) {
            case 0: src = Wq; dst = wt; break;
            case 1: src = Wk; dst = wt + (1u << 20); break;
            case 2: src = Wv; dst = wt + (2u << 20); break;
            case 3: src = Wz; dst = wt + (3u << 20); break;
            case 4: src = Wr; dst = wt + (4u << 20); break;
            default: src = Wo; dst = wt + (5u << 20); break;
        }
    } else if (bid < 10240) {
        t = bid - 6144; K = 1024; nlg = 7; src = W1; dst = wt + (6u << 20);
    } else {
        t = bid - 10240; K = 4096; nlg = 5; src = W2; dst = wt + (10u << 20);
    }
    const int N = 1 << (nlg + 5);
    const int k0 = (t >> nlg) * 32, n0 = (t & ((1 << nlg) - 1)) * 32;
    const int c = threadIdx.x & 31, r8 = threadIdx.x >> 5;
    #pragma unroll
    for (int it = 0; it < 4; it++)
        s[r8 + it*8][c] = src[(long)(k0 + r8 + it*8) * N + n0 + c];
    __syncthreads();
    #pragma unroll
    for (int it = 0; it < 4; it++)
        dst[(long)(n0 + r8 + it*8) * K + k0 + c] = (bf16)s[c][r8 + it*8];
}

#define MFMA16(a, b, c) __builtin_amdgcn_mfma_f32_16x16x32_bf16(a, b, c, 0, 0, 0)
#define MFMA32(a, b, c) __builtin_amdgcn_mfma_f32_32x32x16_bf16(a, b, c, 0, 0, 0)

// ====== 256x128 GEMM core v5: 3 LDS buffers, ONE barrier/kt (BK=32, 8 waves, 72 KiB) ======
// Stage kt+2 -> buf[(kt+2)%3] = buf[(kt-1)%3]: all reads of that buf retired before any
// wave passed this kt's top barrier (each wave's LGKM0 precedes its MFMAs precedes BAR).
// Ledger (3 loads/stage): invariant outstanding at top-BAR = next tile's 3 loads.
__device__ __forceinline__ void gemm128_core(const bf16* __restrict__ A, const bf16* __restrict__ Bt,
        const int Ks, const int NT, const int m0, const int n0, char* lds, f32x4 (&acc)[4][4]) {
    const int tid = threadIdx.x;
    const int lane = tid & 63, w = tid >> 6;
    const int wm = w >> 1, wn = w & 1;
    const int cl = lane & 15, gl = lane >> 4;
    const int srow = lane >> 2;
    const int sxc = (((lane & 3) ^ ((lane >> 3) & 3)) << 3);   // chunk ^= (row>>1)&3
    const bf16* pa0 = A  + (size_t)(m0 + w * 32 + srow) * Ks + sxc;
    const bf16* pa1 = pa0 + (size_t)16 * Ks;
    const bf16* pb  = Bt + (size_t)(n0 + w * 16 + srow) * Ks + sxc;
    char* laA = lds + w * 2048;
    char* laB = lds + 49152 + w * 1024;

#define STG(KT) do { const int b3_ = (KT) % 3; \
    gload_lds16(pa0 + (size_t)(KT) * 32, laA + b3_ * 16384); \
    gload_lds16(pa1 + (size_t)(KT) * 32, laA + b3_ * 16384 + 1024); \
    gload_lds16(pb  + (size_t)(KT) * 32, laB + b3_ * 8192); } while (0)

    STG(0); STG(1);
    VMC(3);

    const int xo  = ((gl ^ ((cl >> 1) & 3)) << 4);
    const int rdA = (wm * 64 + cl) * 64 + xo;
    const int rdB = (wn * 64 + cl) * 64 + xo;

    for (int kt = 0; kt < NT; ++kt) {
        const int buf = kt % 3;
        const char* sA = lds + buf * 16384;
        const char* sB = lds + 49152 + buf * 8192;
        BAR();                                   // buf[kt%3] staged; all waves past kt-1
        bf16x8 a[4], b[4];
        #pragma unroll
        for (int mi = 0; mi < 4; mi++) a[mi] = *(const bf16x8*)(sA + rdA + mi * 1024);
        #pragma unroll
        for (int ni = 0; ni < 4; ni++) b[ni] = *(const bf16x8*)(sB + rdB + ni * 1024);
        LGKM0();
        __builtin_amdgcn_sched_barrier(0);       // fence: keep MFMA after lgkmcnt (rule 18)
        if (kt + 2 < NT) STG(kt + 2);
        __builtin_amdgcn_s_setprio(1);
        #pragma unroll
        for (int mi = 0; mi < 4; mi++)
            #pragma unroll
            for (int ni = 0; ni < 4; ni++)
                acc[mi][ni] = MFMA16(a[mi], b[ni], acc[mi][ni]);
        __builtin_amdgcn_s_setprio(0);
        if (kt + 2 < NT)      { VMC(3); }
        else if (kt + 1 < NT) { VMC(0); }
    }
#undef STG
}

// ====== 128x128 GEMM core: 3 buffers, ONE barrier/kt (4 waves, BK=32, 48 KiB) ======
__device__ __forceinline__ void gemm64_core(const bf16* __restrict__ A, const bf16* __restrict__ Bt,
        const int Ks, const int NT, const int m0, const int n0, char* lds, f32x4 (&acc)[4][4]) {
    const int tid = threadIdx.x;                 // 256 threads, 4 waves
    const int lane = tid & 63, w = tid >> 6;
    const int wm = w >> 1, wn = w & 1;
    const int cl = lane & 15, gl = lane >> 4;
    const int srow = tid >> 2;                   // 0..63
    const int sxc = (((tid & 3) ^ ((tid >> 3) & 3)) << 3);
    const bf16* pa0 = A  + (size_t)(m0 + srow) * Ks + sxc;
    const bf16* pa1 = pa0 + (size_t)64 * Ks;
    const bf16* pb0 = Bt + (size_t)(n0 + srow) * Ks + sxc;
    const bf16* pb1 = pb0 + (size_t)64 * Ks;
    char* laA = lds + w * 1024;
    char* laB = lds + 24576 + w * 1024;

#define STG(KT) do { const int b3_ = (KT) % 3; \
    gload_lds16(pa0 + (size_t)(KT) * 32, laA + b3_ * 8192); \
    gload_lds16(pa1 + (size_t)(KT) * 32, laA + b3_ * 8192 + 4096); \
    gload_lds16(pb0 + (size_t)(KT) * 32, laB + b3_ * 8192); \
    gload_lds16(pb1 + (size_t)(KT) * 32, laB + b3_ * 8192 + 4096); } while (0)

    STG(0); STG(1);
    VMC(4);

    const int xo  = ((gl ^ ((cl >> 1) & 3)) << 4);
    const int rdA = (wm * 64 + cl) * 64 + xo;
    const int rdB = (wn * 64 + cl) * 64 + xo;

    for (int kt = 0; kt < NT; ++kt) {
        const int buf = kt % 3;
        const char* sA = lds + buf * 8192;
        const char* sB = lds + 24576 + buf * 8192;
        BAR();
        bf16x8 a[4], b[4];
        #pragma unroll
        for (int mi = 0; mi < 4; mi++) a[mi] = *(const bf16x8*)(sA + rdA + mi * 1024);
        #pragma unroll
        for (int ni = 0; ni < 4; ni++) b[ni] = *(const bf16x8*)(sB + rdB + ni * 1024);
        LGKM0();
        __builtin_amdgcn_sched_barrier(0);
        if (kt + 2 < NT) STG(kt + 2);
        __builtin_amdgcn_s_setprio(1);
        #pragma unroll
        for (int mi = 0; mi < 4; mi++)
            #pragma unroll
            for (int ni = 0; ni < 4; ni++)
                acc[mi][ni] = MFMA16(a[mi], b[ni], acc[mi][ni]);
        __builtin_amdgcn_s_setprio(0);
        if (kt + 2 < NT)      { VMC(4); }
        else if (kt + 1 < NT) { VMC(0); }
    }
#undef STG
}

// =============== 256x256 8-phase GEMM core (BK=64, 8 waves, 128 KiB LDS) ===============
__device__ __forceinline__ void gemm256_core(const bf16* __restrict__ A, const bf16* __restrict__ Bt,
        const int Ks, const int NT, const int m0, const int n0, char* lds, f32x4 (&acc)[8][4]) {
    const int tid = threadIdx.x;
    const int lane = tid & 63, w = tid >> 6;
    const int wm = w >> 2, wn = w & 3;
    const int cl = lane & 15, gl = lane >> 4;
    const int srow = lane >> 3;
    const int scol = ((lane & 7) ^ srow) * 8;
    const bf16* pa0 = A  + (size_t)(m0 + w * 16 + srow) * Ks + scol;
    const bf16* pa1 = pa0 + (size_t)8 * Ks;
    const bf16* pb0 = Bt + (size_t)(n0 + w * 16 + srow) * Ks + scol;
    const bf16* pb1 = pb0 + (size_t)8 * Ks;
    char* la = lds + w * 2048;
    char* lb = lds + 65536 + w * 2048;
    const size_t hA = (size_t)128 * Ks;

#define STGA(H, KT, BUF) do { \
    gload_lds16(pa0 + (size_t)(H) * hA + (size_t)(KT) * 64, la + (BUF) * 32768 + (H) * 16384); \
    gload_lds16(pa1 + (size_t)(H) * hA + (size_t)(KT) * 64, la + (BUF) * 32768 + (H) * 16384 + 1024); } while (0)
#define STGB(H, KT, BUF) do { \
    gload_lds16(pb0 + (size_t)(H) * hA + (size_t)(KT) * 64, lb + (BUF) * 32768 + (H) * 16384); \
    gload_lds16(pb1 + (size_t)(H) * hA + (size_t)(KT) * 64, lb + (BUF) * 32768 + (H) * 16384 + 1024); } while (0)

    STGA(0, 0, 0); STGA(1, 0, 0); STGB(0, 0, 0); STGB(1, 0, 0);
    STGB(0, 1, 1); STGA(0, 1, 1); STGA(1, 1, 1);
    VMC(6);
    BAR();

    const int X0  = (gl * 16) ^ ((cl & 7) << 4);
    const int rdA = (wm * 128 + cl) * 128 + X0;
    const int rdB = (wn * 64  + cl) * 128 + X0;

    for (int kt = 0; kt < NT; ++kt) {
        const int buf = kt & 1;
        const char* sAb = lds + buf * 32768;
        const char* sBb = lds + 65536 + buf * 32768;
        const bool st1 = (kt + 1 < NT), st2 = (kt + 2 < NT);
        bf16x8 a0[4][2], a4[4][2], b01[2][2], b23[2][2];
        #pragma unroll
        for (int mi = 0; mi < 4; mi++) {
            a0[mi][0] = *(const bf16x8*)(sAb + rdA + mi * 2048);
            a0[mi][1] = *(const bf16x8*)(sAb + (rdA ^ 64) + mi * 2048);
        }
        #pragma unroll
        for (int ni = 0; ni < 2; ni++) {
            b01[ni][0] = *(const bf16x8*)(sBb + rdB + ni * 2048);
            b01[ni][1] = *(const bf16x8*)(sBb + (rdB ^ 64) + ni * 2048);
        }
        if (st1) STGB(1, kt + 1, buf ^ 1);
        BAR(); LGKM0();
        __builtin_amdgcn_s_setprio(1);
        #pragma unroll
        for (int mi = 0; mi < 4; mi++)
            #pragma unroll
            for (int ni = 0; ni < 2; ni++) {
                acc[mi][ni] = MFMA16(a0[mi][0], b01[ni][0], acc[mi][ni]);
                acc[mi][ni] = MFMA16(a0[mi][1], b01[ni][1], acc[mi][ni]);
            }
        __builtin_amdgcn_s_setprio(0);
        BAR();
        #pragma unroll
        for (int mi = 0; mi < 4; mi++) {
            a4[mi][0] = *(const bf16x8*)(sAb + rdA + (mi + 4) * 2048);
            a4[mi][1] = *(const bf16x8*)(sAb + (rdA ^ 64) + (mi + 4) * 2048);
        }
        BAR(); LGKM0();
        __builtin_amdgcn_s_setprio(1);
        #pragma unroll
        for (int mi = 0; mi < 4; mi++)
            #pragma unroll
            for (int ni = 0; ni < 2; ni++) {
                acc[mi + 4][ni] = MFMA16(a4[mi][0], b01[ni][0], acc[mi + 4][ni]);
                acc[mi + 4][ni] = MFMA16(a4[mi][1], b01[ni][1], acc[mi + 4][ni]);
            }
        __builtin_amdgcn_s_setprio(0);
        BAR();
        #pragma unroll
        for (int ni = 0; ni < 2; ni++) {
            b23[ni][0] = *(const bf16x8*)(sBb + rdB + (ni + 2) * 2048);
            b23[ni][1] = *(const bf16x8*)(sBb + (rdB ^ 64) + (ni + 2) * 2048);
        }
        if (st2) STGA(0, kt + 2, buf);
        BAR(); LGKM0();
        __builtin_amdgcn_s_setprio(1);
        #pragma unroll
        for (int mi = 0; mi < 4; mi++)
            #pragma unroll
            for (int ni = 0; ni < 2; ni++) {
                acc[mi + 4][ni + 2] = MFMA16(a4[mi][0], b23[ni][0], acc[mi + 4][ni + 2]);
                acc[mi + 4][ni + 2] = MFMA16(a4[mi][1], b23[ni][1], acc[mi + 4][ni + 2]);
            }
        __builtin_amdgcn_s_setprio(0);
        BAR();
        if (st2) { STGA(1, kt + 2, buf); STGB(0, kt + 2, buf); }
        __builtin_amdgcn_s_setprio(1);
        #pragma unroll
        for (int mi = 0; mi < 4; mi++)
            #pragma unroll
            for (int ni = 0; ni < 2; ni++) {
                acc[mi][ni + 2] = MFMA16(a0[mi][0], b23[ni][0], acc[mi][ni + 2]);
                acc[mi][ni + 2] = MFMA16(a0[mi][1], b23[ni][1], acc[mi][ni + 2]);
            }
        __builtin_amdgcn_s_setprio(0);
        if (st2)      { VMC(6); }
        else if (st1) { VMC(0); }
        BAR();
    }
#undef STGA
#undef STGB
}

// ---- gemm5: xn[4096,1024] @ wt[5120,1024]^T, segmented epilogue. grid 640 x 512 thr (v5) ----
__global__ __launch_bounds__(512, 4) void gemm5_k(const bf16* __restrict__ A, const bf16* __restrict__ Bt,
        const float* __restrict__ bq, const float* __restrict__ bk, const float* __restrict__ bvv,
        const float* __restrict__ bz, const float* __restrict__ br,
        bf16* __restrict__ oq, bf16* __restrict__ ok, bf16* __restrict__ ov,
        bf16* __restrict__ oz, bf16* __restrict__ orr) {
    __shared__ __align__(16) char lds[73728];
    int bid = blockIdx.x;
    bid = (bid & 7) * 80 + (bid >> 3);
    const int m0 = (bid / 40) * 256, n0 = (bid % 40) * 128;
    f32x4 acc[4][4];
    #pragma unroll
    for (int i = 0; i < 4; i++)
        #pragma unroll
        for (int j = 0; j < 4; j++) acc[i][j] = (f32x4){0.f, 0.f, 0.f, 0.f};
    gemm128_core(A, Bt, 1024, 32, m0, n0, lds, acc);
    const int tid = threadIdx.x, lane = tid & 63, w = tid >> 6;
    const int wm = w >> 1, wn = w & 1, cl = lane & 15, gl = lane >> 4;
    const int seg = n0 >> 10;
    const int lc0 = (n0 & 1023) + wn * 64;
    const float* bias; int mode; bf16* outp;
    switch (seg) {
        case 0:  bias = bq;  mode = 0; outp = oq;  break;
        case 1:  bias = bk;  mode = 0; outp = ok;  break;
        case 2:  bias = bvv; mode = 1; outp = ov;  break;
        case 3:  bias = bz;  mode = 2; outp = oz;  break;
        default: bias = br;  mode = 2; outp = orr; break;
    }
    const float scl = (seg == 0) ? 0.125f : 1.0f;   // pre-scale Q for attention
    #pragma unroll
    for (int mi = 0; mi < 4; mi++) {
        #pragma unroll
        for (int ni = 0; ni < 4; ni++) {
            const int lcol = lc0 + ni * 16 + cl;
            const float bv = bias[lcol];
            #pragma unroll
            for (int r = 0; r < 4; r++) {
                const int row = m0 + wm * 64 + mi * 16 + gl * 4 + r;
                const float v = (acc[mi][ni][r] + bv) * scl;
                if (mode == 0) {
                    outp[(long)row * 1024 + lcol] = (bf16)v;
                } else if (mode == 1) {
                    outp[((long)(row >> 11) * 1024 + lcol) * T_ + (row & 2047)] = (bf16)v;
                } else {
                    outp[(long)row * 1024 + lcol] = (bf16)(1.0f / (1.0f + __expf(-v)));
                }
            }
        }
    }
}

// ---- W1: gelu -> bf16 h1. grid 256 x 512 thr (8-phase) ----
__global__ __launch_bounds__(512, 2) void gemmG8_k(const bf16* __restrict__ A, const bf16* __restrict__ Bt,
        const float* __restrict__ bias, bf16* __restrict__ out) {
    __shared__ __align__(16) char lds[131072];
    int bid = blockIdx.x;
    bid = (bid & 7) * 32 + (bid >> 3);
    const int m0 = (bid >> 4) * 256, n0 = (bid & 15) * 256;
    f32x4 acc[8][4];
    #pragma unroll
    for (int i = 0; i < 8; i++)
        #pragma unroll
        for (int j = 0; j < 4; j++) acc[i][j] = (f32x4){0.f, 0.f, 0.f, 0.f};
    gemm256_core(A, Bt, 1024, 16, m0, n0, lds, acc);
    const int tid = threadIdx.x, lane = tid & 63, w = tid >> 6;
    const int wm = w >> 2, wn = w & 3, cl = lane & 15, gl = lane >> 4;
    #pragma unroll
    for (int mi = 0; mi < 8; mi++) {
        #pragma unroll
        for (int ni = 0; ni < 4; ni++) {
            const int col = n0 + wn * 64 + ni * 16 + cl;
            const float bv = bias[col];
            #pragma unroll
            for (int r = 0; r < 4; r++) {
                const int row = m0 + wm * 128 + mi * 16 + gl * 4 + r;
                float v = acc[mi][ni][r] + bv;
                v = 0.5f * v * (1.0f + erff(v * 0.70710678118f));
                out[(long)row * DF_ + col] = (bf16)v;
            }
        }
    }
}

// ---- W2 split-K=4 -> 4 bf16 partials. grid 256 x 512 thr (8-phase) ----
__global__ __launch_bounds__(512, 2) void gemmP8_k(const bf16* __restrict__ A, const bf16* __restrict__ Bt,
        bf16* __restrict__ p0, bf16* __restrict__ p1, bf16* __restrict__ p2, bf16* __restrict__ p3) {
    __shared__ __align__(16) char lds[131072];
    int bid = blockIdx.x;
    bid = (bid & 7) * 32 + (bid >> 3);
    const int mt = bid >> 4, rest = bid & 15;
    const int nt = rest >> 2, s = rest & 3;
    const int m0 = mt * 256, n0 = nt * 256;
    f32x4 acc[8][4];
    #pragma unroll
    for (int i = 0; i < 8; i++)
        #pragma unroll
        for (int j = 0; j < 4; j++) acc[i][j] = (f32x4){0.f, 0.f, 0.f, 0.f};
    gemm256_core(A + s * 1024, Bt + s * 1024, 4096, 16, m0, n0, lds, acc);
    bf16* outp = (s == 0) ? p0 : (s == 1) ? p1 : (s == 2) ? p2 : p3;
    const int tid = threadIdx.x, lane = tid & 63, w = tid >> 6;
    const int wm = w >> 2, wn = w & 3, cl = lane & 15, gl = lane >> 4;
    #pragma unroll
    for (int mi = 0; mi < 8; mi++) {
        #pragma unroll
        for (int ni = 0; ni < 4; ni++) {
            const int col = n0 + wn * 64 + ni * 16 + cl;
            #pragma unroll
            for (int r = 0; r < 4; r++) {
                const int row = m0 + wm * 128 + mi * 16 + gl * 4 + r;
                outp[(long)row * 1024 + col] = (bf16)acc[mi][ni][r];
            }
        }
    }
}

// ---- Wo GEMM (128x128 4-wave 3-buf core) with fused gate1 epilogue. grid 256 x 256 thr ----
__global__ __launch_bounds__(256, 4) void gemmWoG_kernel(const bf16* __restrict__ A,
        const bf16* __restrict__ Bt, const float* __restrict__ bias,
        float* __restrict__ x, const bf16* __restrict__ z, const bf16* __restrict__ rr) {
    __shared__ __align__(16) char lds[49152];
    int bid = blockIdx.x;
    bid = (bid & 7) * 32 + (bid >> 3);            // 256 blocks, bijective
    const int m0 = (bid >> 3) * 128, n0 = (bid & 7) * 128;
    f32x4 acc[4][4];
    #pragma unroll
    for (int i = 0; i < 4; i++)
        #pragma unroll
        for (int j = 0; j < 4; j++) acc[i][j] = (f32x4){0.f, 0.f, 0.f, 0.f};
    gemm64_core(A, Bt, 1024, 32, m0, n0, lds, acc);
    const int tid = threadIdx.x, lane = tid & 63, w = tid >> 6;
    const int wm = w >> 1, wn = w & 1, cl = lane & 15, gl = lane >> 4;
    #pragma unroll
    for (int mi = 0; mi < 4; mi++) {
        #pragma unroll
        for (int ni = 0; ni < 4; ni++) {
            const int col = n0 + wn * 64 + ni * 16 + cl;
            const float bv = bias[col];
            #pragma unroll
            for (int r = 0; r < 4; r++) {
                const int row = m0 + wm * 64 + mi * 16 + gl * 4 + r;
                const long idx = (long)row * D_ + col;
                const float xa = acc[mi][ni][r] + bv;
                const float zv = (float)z[idx];
                const float ht = tanhf((float)rr[idx] * xa);
                x[idx] = (1.f - zv) * x[idx] + zv * ht;
            }
        }
    }
}

// ======= Flash attention v2 (unchanged) =======
__global__ __launch_bounds__(256, 2) void attn_kernel(const bf16* __restrict__ q,
        const bf16* __restrict__ k, const bf16* __restrict__ vT,
        bf16* __restrict__ y) {
    __shared__ __align__(16) char lds[32768];
    const int tid = threadIdx.x, wid = tid >> 6, lane = tid & 63;
    const int col = lane & 31, hi = lane >> 5;
    const int bid = blockIdx.x;
    const int xcd = bid & 7, idx = bid >> 3;
    const int bh = xcd + 8 * (idx & 3);
    const int sg = idx >> 2;
    const int g = (sg & 1) ? (sg >> 1) : (15 - (sg >> 1));
    const int qt = 4 * g + wid;
    const int qb = qt * 32;
    const int b = bh >> 4, h = bh & 15;
    const int NP = 2 * g + 2;
    const int nt64 = (qt >> 1) + 1;

    const bf16* qB = q  + (size_t)b * T_ * D_ + h * HD_;
    const bf16* kB = k  + (size_t)b * T_ * D_ + h * HD_;
    const bf16* vB = vT + (size_t)b * D_ * T_ + (size_t)h * HD_ * T_;

    const int sr = wid * 8 + (lane >> 3);
    const int sc = lane & 7;
    const bf16* kS0 = kB + (size_t)sr * D_ + 8 * (sc ^ (sr & 7));
    const bf16* kS1 = kS0 + (size_t)32 * D_;
    const bf16* vS0 = vB + (size_t)sr * T_ + 8 * (sc ^ (sr & 7));
    const bf16* vS1 = vS0 + (size_t)32 * T_;
    char* dK = lds + wid * 1024;
    char* dV = lds + 16384 + wid * 1024;

#define ASTG(J, BUF) do { \
    const size_t ko_ = (size_t)(J) * 64 * D_; \
    const size_t vo_ = (size_t)(J) * 64; \
    gload_lds16(kS0 + ko_, dK + (BUF) * 8192); \
    gload_lds16(kS1 + ko_, dK + (BUF) * 8192 + 4096); \
    gload_lds16(vS0 + vo_, dV + (BUF) * 8192); \
    gload_lds16(vS1 + vo_, dV + (BUF) * 8192 + 4096); } while (0)

    bf16x8 qf0, qf1, qf2, qf3;
    {
        const bf16* qp = qB + (size_t)(qb + col) * D_ + 8 * hi;
        qf0 = *(const bf16x8*)(qp);
        qf1 = *(const bf16x8*)(qp + 16);
        qf2 = *(const bf16x8*)(qp + 32);
        qf3 = *(const bf16x8*)(qp + 48);
    }

    f32x16 Od0, Od1;
    #pragma unroll
    for (int i = 0; i < 16; i++) { Od0[i] = 0.f; Od1[i] = 0.f; }
    float mrun = -INFINITY, lrun = 0.f;

    ASTG(0, 0);
    ASTG(1, 1);
    VMC(4);
    BAR();

    const int swz = col & 7;
    for (int j = 0; j < NP; ++j) {
        const int buf = j & 1;
        if (j < nt64) {
            const char* bK = lds + buf * 8192;
            const char* bV = lds + 16384 + buf * 8192;
            bf16x8 kf0[4], kf1[4], vf0[4], vf1[4];
            #pragma unroll
            for (int cs = 0; cs < 4; cs++) {
                const int ch = ((hi + 2 * cs) ^ swz) * 16;
                kf0[cs] = *(const bf16x8*)(bK + col * 128 + ch);
                kf1[cs] = *(const bf16x8*)(bK + (col + 32) * 128 + ch);
                vf0[cs] = *(const bf16x8*)(bV + col * 128 + ch);
                vf1[cs] = *(const bf16x8*)(bV + (col + 32) * 128 + ch);
            }
            f32x16 S0, S1;
            #pragma unroll
            for (int i = 0; i < 16; i++) { S0[i] = 0.f; S1[i] = 0.f; }
            S0 = MFMA32(kf0[0], qf0, S0); S0 = MFMA32(kf0[1], qf1, S0);
            S0 = MFMA32(kf0[2], qf2, S0); S0 = MFMA32(kf0[3], qf3, S0);
            S1 = MFMA32(kf1[0], qf0, S1); S1 = MFMA32(kf1[1], qf1, S1);
            S1 = MFMA32(kf1[2], qf2, S1); S1 = MFMA32(kf1[3], qf3, S1);
            float p[32];
            #pragma unroll
            for (int r = 0; r < 16; r++) { p[r] = S0[r]; p[16 + r] = S1[r]; }
            if (j == nt64 - 1) {
                const int qr = qb + col;
                #pragma unroll
                for (int r = 0; r < 32; r++) {
                    const int kvl = 64 * j + 32 * (r >> 4)
                                  + (r & 3) + 8 * ((r & 15) >> 2) + 4 * hi;
                    if (kvl > qr) p[r] = -3.0e38f;
                }
            }
            float tm = p[0];
            #pragma unroll
            for (int r = 1; r < 32; r++) tm = fmaxf(tm, p[r]);
            tm = fmaxf(tm, __shfl_xor(tm, 32));
            if (!__all(tm <= mrun + 8.f)) {
                const float mn = fmaxf(mrun, tm);
                const float al = __expf(mrun - mn);
                lrun *= al;
                #pragma unroll
                for (int i = 0; i < 16; i++) { Od0[i] *= al; Od1[i] *= al; }
                mrun = mn;
            }
            float ts = 0.f;
            #pragma unroll
            for (int r = 0; r < 32; r++) { p[r] = __expf(p[r] - mrun); ts += p[r]; }
            ts += __shfl_xor(ts, 32);
            lrun += ts;
            bf16x8 pbf[4];
            #pragma unroll
            for (int t = 0; t < 2; t++) {
                const unsigned pw0 = pk2(p[16*t+0],  p[16*t+1]),  pw1 = pk2(p[16*t+2],  p[16*t+3]);
                const unsigned pw2 = pk2(p[16*t+4],  p[16*t+5]),  pw3 = pk2(p[16*t+6],  p[16*t+7]);
                const unsigned pw4 = pk2(p[16*t+8],  p[16*t+9]),  pw5 = pk2(p[16*t+10], p[16*t+11]);
                const unsigned pw6 = pk2(p[16*t+12], p[16*t+13]), pw7 = pk2(p[16*t+14], p[16*t+15]);
                const unsigned px0 = __shfl_xor((int)pw0, 32), px1 = __shfl_xor((int)pw1, 32);
                const unsigned px2 = __shfl_xor((int)pw2, 32), px3 = __shfl_xor((int)pw3, 32);
                const unsigned px4 = __shfl_xor((int)pw4, 32), px5 = __shfl_xor((int)pw5, 32);
                const unsigned px6 = __shfl_xor((int)pw6, 32), px7 = __shfl_xor((int)pw7, 32);
                const u32x4 c0 = hi ? (u32x4){px2, px3, pw2, pw3} : (u32x4){pw0, pw1, px0, px1};
                const u32x4 c1 = hi ? (u32x4){px6, px7, pw6, pw7} : (u32x4){pw4, pw5, px4, px5};
                pbf[2*t]   = __builtin_bit_cast(bf16x8, c0);
                pbf[2*t+1] = __builtin_bit_cast(bf16x8, c1);
            }
            #pragma unroll
            for (int f = 0; f < 4; f++) {
                Od0 = MFMA32(vf0[f], pbf[f], Od0);
                Od1 = MFMA32(vf1[f], pbf[f], Od1);
            }
        }
        BAR();
        if (j + 2 < NP) { ASTG(j + 2, buf); VMC(4); }
        else            { VMC(0); }
        BAR();
    }

    const float inv = 1.0f / lrun;
    bf16* yr = y + (size_t)(b * T_ + qb + col) * D_ + h * HD_;
    #pragma unroll
    for (int rg = 0; rg < 4; rg++) {
        const int d0 = 8 * rg + 4 * hi;
        uint2 s0 = { pk2(Od0[4*rg] * inv, Od0[4*rg+1] * inv), pk2(Od0[4*rg+2] * inv, Od0[4*rg+3] * inv) };
        *(uint2*)(yr + d0) = s0;
        uint2 s1 = { pk2(Od1[4*rg] * inv, Od1[4*rg+1] * inv), pk2(Od1[4*rg+2] * inv, Od1[4*rg+3] * inv) };
        *(uint2*)(yr + 32 + d0) = s1;
    }
#undef ASTG
}

// ---------------- gate2 (4 bf16 partials, bf16 z) + optional fused ln1 ----------------
template<bool LN>
__global__ __launch_bounds__(256) void gate2ln_kernel(float* __restrict__ x,
        const bf16* __restrict__ z,
        const bf16* __restrict__ p0, const bf16* __restrict__ p1,
        const bf16* __restrict__ p2, const bf16* __restrict__ p3,
        const float* __restrict__ src, const float* __restrict__ b2,
        const float* __restrict__ lw, const float* __restrict__ lb,
        bf16* __restrict__ xn) {
    const int row = blockIdx.x, t = threadIdx.x;
    const long i = (long)row * D_ + t * 4;
    float4 xv = *(const float4*)(x + i);
    const float4 zv = ld4bf(z + i);
    const float4 a0 = ld4bf(p0 + i);
    const float4 a1 = ld4bf(p1 + i);
    const float4 a2 = ld4bf(p2 + i);
    const float4 a3 = ld4bf(p3 + i);
    const float4 sv = *(const float4*)(src + i);
    const float4 bb = *(const float4*)(b2 + t * 4);
    xv.x = (1.f - zv.x) * xv.x + zv.x * (a0.x + a1.x + a2.x + a3.x + bb.x) + sv.x;
    xv.y = (1.f - zv.y) * xv.y + zv.y * (a0.y + a1.y + a2.y + a3.y + bb.y) + sv.y;
    xv.z = (1.f - zv.z) * xv.z + zv.z * (a0.z + a1.z + a2.z + a3.z + bb.z) + sv.z;
    xv.w = (1.f - zv.w) * xv.w + zv.w * (a0.w + a1.w + a2.w + a3.w + bb.w) + sv.w;
    *(float4*)(x + i) = xv;
    if (LN) {
        float s  = xv.x + xv.y + xv.z + xv.w;
        float sq = xv.x*xv.x + xv.y*xv.y + xv.z*xv.z + xv.w*xv.w;
        #pragma unroll
        for (int m = 32; m; m >>= 1) { s += __shfl_xor(s, m); sq += __shfl_xor(sq, m); }
        __shared__ float red[8];
        const int wid = t >> 6, lid = t & 63;
        if (lid == 0) { red[wid] = s; red[wid + 4] = sq; }
        __syncthreads();
        s  = red[0] + red[1] + red[2] + red[3];
        sq = red[4] + red[5] + red[6] + red[7];
        const float mu   = s * (1.0f / D_);
        const float var  = sq * (1.0f / D_) - mu * mu;
        const float rstd = rsqrtf(var + 1e-5f);
        const float4 wv = *(const float4*)(lw + t * 4);
        const float4 bv = *(const float4*)(lb + t * 4);
        bf16* o = xn + i;
        o[0] = (bf16)((xv.x - mu) * rstd * wv.x + bv.x);
        o[1] = (bf16)((xv.y - mu) * rstd * wv.y + bv.y);
        o[2] = (bf16)((xv.z - mu) * rstd * wv.z + bv.z);
        o[3] = (bf16)((xv.w - mu) * rstd * wv.w + bv.w);
    }
}

extern "C" void kernel_launch(void* const* d_in, const int* in_sizes, int n_in,
                              void* d_out, int out_size, void* d_ws, size_t ws_size,
                              hipStream_t stream) {
    const float* seq   = (const float*)d_in[0];
    const float* Wq    = (const float*)d_in[1];  const float* bq = (const float*)d_in[2];
    const float* Wk    = (const float*)d_in[3];  const float* bk = (const float*)d_in[4];
    const float* Wv    = (const float*)d_in[5];  const float* bv = (const float*)d_in[6];
    const float* Wo    = (const float*)d_in[7];  const float* bo = (const float*)d_in[8];
    const float* Wz    = (const float*)d_in[9];  const float* bz = (const float*)d_in[10];
    const float* Wr    = (const float*)d_in[11]; const float* br = (const float*)d_in[12];
    const float* W1    = (const float*)d_in[13]; const float* b1 = (const float*)d_in[14];
    const float* W2    = (const float*)d_in[15]; const float* b2 = (const float*)d_in[16];
    const float* ln1w  = (const float*)d_in[17]; const float* ln1b = (const float*)d_in[18];
    const float* ln2w  = (const float*)d_in[19]; const float* ln2b = (const float*)d_in[20];
    const float* lnfw  = (const float*)d_in[21]; const float* lnfb = (const float*)d_in[22];

    char* ws = (char*)d_ws;
    float* x   = (float*)(ws);                       // 16 MB
    bf16*  z   = (bf16*)(ws + ((size_t)16 << 20));   // 8 MB
    bf16*  r   = (bf16*)(ws + ((size_t)32 << 20));   // 8 MB (W2 partial 1)
    bf16*  xa  = (bf16*)(ws + ((size_t)48 << 20));   // 8 MB (W2 partial 0)
    bf16*  xn  = (bf16*)(ws + ((size_t)64 << 20));   // 8 MB
    bf16*  qb_ = (bf16*)(ws + ((size_t)72 << 20));   // 8 MB
    bf16*  kb_ = (bf16*)(ws + ((size_t)80 << 20));   // 8 MB
    bf16*  vtb = (bf16*)(ws + ((size_t)88 << 20));   // 8 MB
    bf16*  yb  = (bf16*)(ws + ((size_t)96 << 20));   // 8 MB
    bf16*  h1  = (bf16*)(ws + ((size_t)104 << 20));  // 32 MB
    bf16*  wt  = (bf16*)(ws + ((size_t)136 << 20));  // 36 MB weight pool
    bf16*  pt2 = (bf16*)(ws + ((size_t)172 << 20));  // 8 MB (W2 partial 2)
    bf16*  pt3 = (bf16*)(ws + ((size_t)188 << 20));  // 8 MB (W2 partial 3)

    bf16* wto = wt + (5u << 20);
    bf16* wt1 = wt + (6u << 20);
    bf16* wt2 = wt + (10u << 20);

    hipMemcpyAsync(x, seq, (size_t)M_ * D_ * 4, hipMemcpyDeviceToDevice, stream);

    for (int i = 0; i < NL_; i++) {
        const long dd = (long)i * D_ * D_;
        wconv_all<<<14336, 256, 0, stream>>>(Wq + dd, Wk + dd, Wv + dd, Wz + dd,
                                             Wr + dd, Wo + dd,
                                             W1 + (long)i * D_ * DF_,
                                             W2 + (long)i * DF_ * D_, wt);
        if (i == 0)
            ln_kernel<true><<<M_, 256, 0, stream>>>(x, ln1w, ln1b, xn);
        gemm5_k<<<640, 512, 0, stream>>>(xn, wt,
                bq + i * D_, bk + i * D_, bv + i * D_, bz + i * D_, br + i * D_,
                qb_, kb_, vtb, z, r);
        attn_kernel<<<512, 256, 0, stream>>>(qb_, kb_, vtb, yb);
        gemmWoG_kernel<<<256, 256, 0, stream>>>(yb, wto, bo + i * D_, x, z, r);
        ln_kernel<true><<<M_, 256, 0, stream>>>(x, ln2w + i * D_, ln2b + i * D_, xn);
        gemmG8_k<<<256, 512, 0, stream>>>(xn, wt1, b1 + i * DF_, h1);
        gemmP8_k<<<256, 512, 0, stream>>>(h1, wt2, xa, r, pt2, pt3);
        if (i + 1 < NL_)
            gate2ln_kernel<true><<<M_, 256, 0, stream>>>(x, z, xa, r, pt2, pt3, seq, b2 + i * D_,
                    ln1w + (i + 1) * D_, ln1b + (i + 1) * D_, xn);
        else
            gate2ln_kernel<false><<<M_, 256, 0, stream>>>(x, z, xa, r, pt2, pt3, seq, b2 + i * D_,
                    nullptr, nullptr, nullptr);
    }
    ln_kernel<false><<<M_, 256, 0, stream>>>(x, lnfw, lnfb, d_out);
}

// Round 18
// 1668.793 us; speedup vs baseline: 1.0055x; 1.0055x over previous
//
#include <hip/hip_runtime.h>
#include <hip/hip_bf16.h>
#include <math.h>

#define B_ 2
#define T_ 2048
#define D_ 1024
#define H_ 16
#define NL_ 6
#define DF_ 4096
#define HD_ 64
#define M_ (B_*T_)

typedef __bf16 bf16;
typedef __attribute__((ext_vector_type(8))) __bf16 bf16x8;
typedef __attribute__((ext_vector_type(4))) float f32x4;
typedef __attribute__((ext_vector_type(16))) float f32x16;
typedef __attribute__((ext_vector_type(4))) unsigned u32x4;

#define BAR() __builtin_amdgcn_s_barrier()
#define LGKM0() asm volatile("s_waitcnt lgkmcnt(0)" ::: "memory")
#define VMC(n) asm volatile("s_waitcnt vmcnt(" #n ")" ::: "memory")

__device__ __forceinline__ void gload_lds16(const void* g, void* l) {
    __builtin_amdgcn_global_load_lds((const __attribute__((address_space(1))) void*)g,
                                     (__attribute__((address_space(3))) void*)l, 16, 0, 0);
}

__device__ __forceinline__ unsigned pk2(float a, float b) {
    bf16 lo = (bf16)a, hb = (bf16)b;
    return (unsigned)__builtin_bit_cast(unsigned short, lo) |
           ((unsigned)__builtin_bit_cast(unsigned short, hb) << 16);
}

__device__ __forceinline__ float4 ld4bf(const bf16* p) {
    float4 o;
    o.x = (float)p[0]; o.y = (float)p[1]; o.z = (float)p[2]; o.w = (float)p[3];
    return o;
}

// ---------------- LayerNorm ----------------
template<bool OUT_BF16>
__global__ __launch_bounds__(256) void ln_kernel(const float* __restrict__ x,
        const float* __restrict__ w, const float* __restrict__ b,
        void* __restrict__ out) {
    const int row = blockIdx.x;
    const int t = threadIdx.x;
    const float4 xv = *(const float4*)(x + (long)row * D_ + t * 4);
    float s  = xv.x + xv.y + xv.z + xv.w;
    float sq = xv.x*xv.x + xv.y*xv.y + xv.z*xv.z + xv.w*xv.w;
    #pragma unroll
    for (int m = 32; m; m >>= 1) { s += __shfl_xor(s, m); sq += __shfl_xor(sq, m); }
    __shared__ float red[8];
    const int wid = t >> 6, lid = t & 63;
    if (lid == 0) { red[wid] = s; red[wid + 4] = sq; }
    __syncthreads();
    s  = red[0] + red[1] + red[2] + red[3];
    sq = red[4] + red[5] + red[6] + red[7];
    const float mu   = s * (1.0f / D_);
    const float var  = sq * (1.0f / D_) - mu * mu;
    const float rstd = rsqrtf(var + 1e-5f);
    const float4 wv = *(const float4*)(w + t * 4);
    const float4 bv = *(const float4*)(b + t * 4);
    float o0 = (xv.x - mu) * rstd * wv.x + bv.x;
    float o1 = (xv.y - mu) * rstd * wv.y + bv.y;
    float o2 = (xv.z - mu) * rstd * wv.z + bv.z;
    float o3 = (xv.w - mu) * rstd * wv.w + bv.w;
    if (OUT_BF16) {
        bf16* o = (bf16*)out + (long)row * D_ + t * 4;
        o[0] = (bf16)o0; o[1] = (bf16)o1; o[2] = (bf16)o2; o[3] = (bf16)o3;
    } else {
        float* o = (float*)out + (long)row * D_ + t * 4;
        o[0] = o0; o[1] = o1; o[2] = o2; o[3] = o3;
    }
}

// ---------------- first LN: x = seq (copy) + xn = LN(seq) in one pass ----------------
__global__ __launch_bounds__(256) void ln_first_kernel(const float* __restrict__ seq,
        const float* __restrict__ w, const float* __restrict__ b,
        float* __restrict__ x, bf16* __restrict__ xn) {
    const int row = blockIdx.x;
    const int t = threadIdx.x;
    const float4 xv = *(const float4*)(seq + (long)row * D_ + t * 4);
    *(float4*)(x + (long)row * D_ + t * 4) = xv;
    float s  = xv.x + xv.y + xv.z + xv.w;
    float sq = xv.x*xv.x + xv.y*xv.y + xv.z*xv.z + xv.w*xv.w;
    #pragma unroll
    for (int m = 32; m; m >>= 1) { s += __shfl_xor(s, m); sq += __shfl_xor(sq, m); }
    __shared__ float red[8];
    const int wid = t >> 6, lid = t & 63;
    if (lid == 0) { red[wid] = s; red[wid + 4] = sq; }
    __syncthreads();
    s  = red[0] + red[1] + red[2] + red[3];
    sq = red[4] + red[5] + red[6] + red[7];
    const float mu   = s * (1.0f / D_);
    const float var  = sq * (1.0f / D_) - mu * mu;
    const float rstd = rsqrtf(var + 1e-5f);
    const float4 wv = *(const float4*)(w + t * 4);
    const float4 bv = *(const float4*)(b + t * 4);
    bf16* o = xn + (long)row * D_ + t * 4;
    o[0] = (bf16)((xv.x - mu) * rstd * wv.x + bv.x);
    o[1] = (bf16)((xv.y - mu) * rstd * wv.y + bv.y);
    o[2] = (bf16)((xv.z - mu) * rstd * wv.z + bv.z);
    o[3] = (bf16)((xv.w - mu) * rstd * wv.w + bv.w);
}

// ------------- merged weight convert+transpose for one layer -------------
__global__ __launch_bounds__(256) void wconv_all(
        const float* __restrict__ Wq, const float* __restrict__ Wk,
        const float* __restrict__ Wv, const float* __restrict__ Wz,
        const float* __restrict__ Wr, const float* __restrict__ Wo,
        const float* __restrict__ W1, const float* __restrict__ W2,
        bf16* __restrict__ wt) {
    __shared__ float s[32][33];
    const int bid = blockIdx.x;
    const float* src; bf16* dst; int t, K, nlg;
    if (bid < 6144) {
        const int m = bid >> 10; t = bid & 1023; K = 1024; nlg = 5;
        switch (m) {
            case 0: src = Wq; dst = wt; break;
            case 1: src = Wk; dst = wt + (1u << 20); break;
            case 2: src = Wv; dst = wt + (2u << 20); break;
            case 3: src = Wz; dst = wt + (3u << 20); break;
            case 4: src = Wr; dst = wt + (4u << 20); break;
            default: src = Wo; dst = wt + (5u << 20); break;
        }
    } else if (bid < 10240) {
        t = bid - 6144; K = 1024; nlg = 7; src = W1; dst = wt + (6u << 20);
    } else {
        t = bid - 10240; K = 4096; nlg = 5; src = W2; dst = wt + (10u << 20);
    }
    const int N = 1 << (nlg + 5);
    const int k0 = (t >> nlg) * 32, n0 = (t & ((1 << nlg) - 1)) * 32;
    const int c = threadIdx.x & 31, r8 = threadIdx.x >> 5;
    #pragma unroll
    for (int it = 0; it < 4; it++)
        s[r8 + it*8][c] = src[(long)(k0 + r8 + it*8) * N + n0 + c];
    __syncthreads();
    #pragma unroll
    for (int it = 0; it < 4; it++)
        dst[(long)(n0 + r8 + it*8) * K + k0 + c] = (bf16)s[c][r8 + it*8];
}

#define MFMA16(a, b, c) __builtin_amdgcn_mfma_f32_16x16x32_bf16(a, b, c, 0, 0, 0)
#define MFMA32(a, b, c) __builtin_amdgcn_mfma_f32_32x32x16_bf16(a, b, c, 0, 0, 0)

// =============== 256x128 GEMM core v3 (BK=32, 8 waves, 48 KiB LDS, 2 BAR/kt) ===============
__device__ __forceinline__ void gemm128_core(const bf16* __restrict__ A, const bf16* __restrict__ Bt,
        const int Ks, const int NT, const int m0, const int n0, char* lds, f32x4 (&acc)[4][4]) {
    const int tid = threadIdx.x;
    const int lane = tid & 63, w = tid >> 6;
    const int wm = w >> 1, wn = w & 1;
    const int cl = lane & 15, gl = lane >> 4;
    const int srow = lane >> 2;
    const int sxc = (((lane & 3) ^ ((lane >> 3) & 3)) << 3);   // chunk ^= (row>>1)&3
    const bf16* pa0 = A  + (size_t)(m0 + w * 32 + srow) * Ks + sxc;
    const bf16* pa1 = pa0 + (size_t)16 * Ks;
    const bf16* pb  = Bt + (size_t)(n0 + w * 16 + srow) * Ks + sxc;
    char* laA = lds + w * 2048;
    char* laB = lds + 32768 + w * 1024;

#define STG(KT, BUF) do { \
    gload_lds16(pa0 + (size_t)(KT) * 32, laA + (BUF) * 16384); \
    gload_lds16(pa1 + (size_t)(KT) * 32, laA + (BUF) * 16384 + 1024); \
    gload_lds16(pb  + (size_t)(KT) * 32, laB + (BUF) * 8192); } while (0)

    STG(0, 0); STG(1, 1);
    VMC(3);

    const int xo  = ((gl ^ ((cl >> 1) & 3)) << 4);
    const int rdA = (wm * 64 + cl) * 64 + xo;
    const int rdB = (wn * 64 + cl) * 64 + xo;

    for (int kt = 0; kt < NT; ++kt) {
        const int buf = kt & 1;
        const char* sA = lds + buf * 16384;
        const char* sB = lds + 32768 + buf * 8192;
        BAR();                                   // buf[kt&1] staged (VMC at prev iter end)
        bf16x8 a[4], b[4];
        #pragma unroll
        for (int mi = 0; mi < 4; mi++) a[mi] = *(const bf16x8*)(sA + rdA + mi * 1024);
        #pragma unroll
        for (int ni = 0; ni < 4; ni++) b[ni] = *(const bf16x8*)(sB + rdB + ni * 1024);
        LGKM0();
        BAR();                                   // all waves' reads retired -> safe to restage
        if (kt + 2 < NT) STG(kt + 2, buf);
        __builtin_amdgcn_s_setprio(1);
        #pragma unroll
        for (int mi = 0; mi < 4; mi++)
            #pragma unroll
            for (int ni = 0; ni < 4; ni++)
                acc[mi][ni] = MFMA16(a[mi], b[ni], acc[mi][ni]);
        __builtin_amdgcn_s_setprio(0);
        if (kt + 2 < NT)      { VMC(3); }
        else if (kt + 1 < NT) { VMC(0); }
    }
#undef STG
}

// =============== 128x128 GEMM core (4 waves, BK=32, 32 KiB LDS, same v3 schedule) ===============
__device__ __forceinline__ void gemm64_core(const bf16* __restrict__ A, const bf16* __restrict__ Bt,
        const int Ks, const int NT, const int m0, const int n0, char* lds, f32x4 (&acc)[4][4]) {
    const int tid = threadIdx.x;                 // 256 threads, 4 waves
    const int lane = tid & 63, w = tid >> 6;
    const int wm = w >> 1, wn = w & 1;           // 2x2 waves of 64x64
    const int cl = lane & 15, gl = lane >> 4;
    const int srow = tid >> 2;                   // 0..63
    const int sxc = (((tid & 3) ^ ((tid >> 3) & 3)) << 3);   // chunk ^= (row>>1)&3 (64-alias safe)
    const bf16* pa0 = A  + (size_t)(m0 + srow) * Ks + sxc;
    const bf16* pa1 = pa0 + (size_t)64 * Ks;
    const bf16* pb0 = Bt + (size_t)(n0 + srow) * Ks + sxc;
    const bf16* pb1 = pb0 + (size_t)64 * Ks;
    char* laA = lds + w * 1024;
    char* laB = lds + 16384 + w * 1024;

#define STG(KT, BUF) do { \
    gload_lds16(pa0 + (size_t)(KT) * 32, laA + (BUF) * 8192); \
    gload_lds16(pa1 + (size_t)(KT) * 32, laA + (BUF) * 8192 + 4096); \
    gload_lds16(pb0 + (size_t)(KT) * 32, laB + (BUF) * 8192); \
    gload_lds16(pb1 + (size_t)(KT) * 32, laB + (BUF) * 8192 + 4096); } while (0)

    STG(0, 0); STG(1, 1);
    VMC(4);

    const int xo  = ((gl ^ ((cl >> 1) & 3)) << 4);
    const int rdA = (wm * 64 + cl) * 64 + xo;    // + mi*1024
    const int rdB = (wn * 64 + cl) * 64 + xo;    // + ni*1024

    for (int kt = 0; kt < NT; ++kt) {
        const int buf = kt & 1;
        const char* sA = lds + buf * 8192;
        const char* sB = lds + 16384 + buf * 8192;
        BAR();
        bf16x8 a[4], b[4];
        #pragma unroll
        for (int mi = 0; mi < 4; mi++) a[mi] = *(const bf16x8*)(sA + rdA + mi * 1024);
        #pragma unroll
        for (int ni = 0; ni < 4; ni++) b[ni] = *(const bf16x8*)(sB + rdB + ni * 1024);
        LGKM0();
        BAR();
        if (kt + 2 < NT) STG(kt + 2, buf);
        __builtin_amdgcn_s_setprio(1);
        #pragma unroll
        for (int mi = 0; mi < 4; mi++)
            #pragma unroll
            for (int ni = 0; ni < 4; ni++)
                acc[mi][ni] = MFMA16(a[mi], b[ni], acc[mi][ni]);
        __builtin_amdgcn_s_setprio(0);
        if (kt + 2 < NT)      { VMC(4); }
        else if (kt + 1 < NT) { VMC(0); }
    }
#undef STG
}

// =============== 256x256 8-phase GEMM core (BK=64, 8 waves, 128 KiB LDS) ===============
__device__ __forceinline__ void gemm256_core(const bf16* __restrict__ A, const bf16* __restrict__ Bt,
        const int Ks, const int NT, const int m0, const int n0, char* lds, f32x4 (&acc)[8][4]) {
    const int tid = threadIdx.x;
    const int lane = tid & 63, w = tid >> 6;
    const int wm = w >> 2, wn = w & 3;
    const int cl = lane & 15, gl = lane >> 4;
    const int srow = lane >> 3;
    const int scol = ((lane & 7) ^ srow) * 8;
    const bf16* pa0 = A  + (size_t)(m0 + w * 16 + srow) * Ks + scol;
    const bf16* pa1 = pa0 + (size_t)8 * Ks;
    const bf16* pb0 = Bt + (size_t)(n0 + w * 16 + srow) * Ks + scol;
    const bf16* pb1 = pb0 + (size_t)8 * Ks;
    char* la = lds + w * 2048;
    char* lb = lds + 65536 + w * 2048;
    const size_t hA = (size_t)128 * Ks;

#define STGA(H, KT, BUF) do { \
    gload_lds16(pa0 + (size_t)(H) * hA + (size_t)(KT) * 64, la + (BUF) * 32768 + (H) * 16384); \
    gload_lds16(pa1 + (size_t)(H) * hA + (size_t)(KT) * 64, la + (BUF) * 32768 + (H) * 16384 + 1024); } while (0)
#define STGB(H, KT, BUF) do { \
    gload_lds16(pb0 + (size_t)(H) * hA + (size_t)(KT) * 64, lb + (BUF) * 32768 + (H) * 16384); \
    gload_lds16(pb1 + (size_t)(H) * hA + (size_t)(KT) * 64, lb + (BUF) * 32768 + (H) * 16384 + 1024); } while (0)

    STGA(0, 0, 0); STGA(1, 0, 0); STGB(0, 0, 0); STGB(1, 0, 0);
    STGB(0, 1, 1); STGA(0, 1, 1); STGA(1, 1, 1);
    VMC(6);
    BAR();

    const int X0  = (gl * 16) ^ ((cl & 7) << 4);
    const int rdA = (wm * 128 + cl) * 128 + X0;
    const int rdB = (wn * 64  + cl) * 128 + X0;

    for (int kt = 0; kt < NT; ++kt) {
        const int buf = kt & 1;
        const char* sAb = lds + buf * 32768;
        const char* sBb = lds + 65536 + buf * 32768;
        const bool st1 = (kt + 1 < NT), st2 = (kt + 2 < NT);
        bf16x8 a0[4][2], a4[4][2], b01[2][2], b23[2][2];
        #pragma unroll
        for (int mi = 0; mi < 4; mi++) {
            a0[mi][0] = *(const bf16x8*)(sAb + rdA + mi * 2048);
            a0[mi][1] = *(const bf16x8*)(sAb + (rdA ^ 64) + mi * 2048);
        }
        #pragma unroll
        for (int ni = 0; ni < 2; ni++) {
            b01[ni][0] = *(const bf16x8*)(sBb + rdB + ni * 2048);
            b01[ni][1] = *(const bf16x8*)(sBb + (rdB ^ 64) + ni * 2048);
        }
        if (st1) STGB(1, kt + 1, buf ^ 1);
        BAR(); LGKM0();
        __builtin_amdgcn_s_setprio(1);
        #pragma unroll
        for (int mi = 0; mi < 4; mi++)
            #pragma unroll
            for (int ni = 0; ni < 2; ni++) {
                acc[mi][ni] = MFMA16(a0[mi][0], b01[ni][0], acc[mi][ni]);
                acc[mi][ni] = MFMA16(a0[mi][1], b01[ni][1], acc[mi][ni]);
            }
        __builtin_amdgcn_s_setprio(0);
        BAR();
        #pragma unroll
        for (int mi = 0; mi < 4; mi++) {
            a4[mi][0] = *(const bf16x8*)(sAb + rdA + (mi + 4) * 2048);
            a4[mi][1] = *(const bf16x8*)(sAb + (rdA ^ 64) + (mi + 4) * 2048);
        }
        BAR(); LGKM0();
        __builtin_amdgcn_s_setprio(1);
        #pragma unroll
        for (int mi = 0; mi < 4; mi++)
            #pragma unroll
            for (int ni = 0; ni < 2; ni++) {
                acc[mi + 4][ni] = MFMA16(a4[mi][0], b01[ni][0], acc[mi + 4][ni]);
                acc[mi + 4][ni] = MFMA16(a4[mi][1], b01[ni][1], acc[mi + 4][ni]);
            }
        __builtin_amdgcn_s_setprio(0);
        BAR();
        #pragma unroll
        for (int ni = 0; ni < 2; ni++) {
            b23[ni][0] = *(const bf16x8*)(sBb + rdB + (ni + 2) * 2048);
            b23[ni][1] = *(const bf16x8*)(sBb + (rdB ^ 64) + (ni + 2) * 2048);
        }
        if (st2) STGA(0, kt + 2, buf);
        BAR(); LGKM0();
        __builtin_amdgcn_s_setprio(1);
        #pragma unroll
        for (int mi = 0; mi < 4; mi++)
            #pragma unroll
            for (int ni = 0; ni < 2; ni++) {
                acc[mi + 4][ni + 2] = MFMA16(a4[mi][0], b23[ni][0], acc[mi + 4][ni + 2]);
                acc[mi + 4][ni + 2] = MFMA16(a4[mi][1], b23[ni][1], acc[mi + 4][ni + 2]);
            }
        __builtin_amdgcn_s_setprio(0);
        BAR();
        if (st2) { STGA(1, kt + 2, buf); STGB(0, kt + 2, buf); }
        __builtin_amdgcn_s_setprio(1);
        #pragma unroll
        for (int mi = 0; mi < 4; mi++)
            #pragma unroll
            for (int ni = 0; ni < 2; ni++) {
                acc[mi][ni + 2] = MFMA16(a0[mi][0], b23[ni][0], acc[mi][ni + 2]);
                acc[mi][ni + 2] = MFMA16(a0[mi][1], b23[ni][1], acc[mi][ni + 2]);
            }
        __builtin_amdgcn_s_setprio(0);
        if (st2)      { VMC(6); }
        else if (st1) { VMC(0); }
        BAR();
    }
#undef STGA
#undef STGB
}

// ---- gemm5: xn[4096,1024] @ wt[5120,1024]^T, segmented epilogue. grid 640 x 512 thr (v3) ----
__global__ __launch_bounds__(512, 4) void gemm5_k(const bf16* __restrict__ A, const bf16* __restrict__ Bt,
        const float* __restrict__ bq, const float* __restrict__ bk, const float* __restrict__ bvv,
        const float* __restrict__ bz, const float* __restrict__ br,
        bf16* __restrict__ oq, bf16* __restrict__ ok, bf16* __restrict__ ov,
        bf16* __restrict__ oz, bf16* __restrict__ orr) {
    __shared__ __align__(16) char lds[49152];
    int bid = blockIdx.x;
    bid = (bid & 7) * 80 + (bid >> 3);
    const int m0 = (bid / 40) * 256, n0 = (bid % 40) * 128;
    f32x4 acc[4][4];
    #pragma unroll
    for (int i = 0; i < 4; i++)
        #pragma unroll
        for (int j = 0; j < 4; j++) acc[i][j] = (f32x4){0.f, 0.f, 0.f, 0.f};
    gemm128_core(A, Bt, 1024, 32, m0, n0, lds, acc);
    const int tid = threadIdx.x, lane = tid & 63, w = tid >> 6;
    const int wm = w >> 1, wn = w & 1, cl = lane & 15, gl = lane >> 4;
    const int seg = n0 >> 10;
    const int lc0 = (n0 & 1023) + wn * 64;
    const float* bias; int mode; bf16* outp;
    switch (seg) {
        case 0:  bias = bq;  mode = 0; outp = oq;  break;
        case 1:  bias = bk;  mode = 0; outp = ok;  break;
        case 2:  bias = bvv; mode = 1; outp = ov;  break;
        case 3:  bias = bz;  mode = 2; outp = oz;  break;
        default: bias = br;  mode = 2; outp = orr; break;
    }
    const float scl = (seg == 0) ? 0.125f : 1.0f;   // pre-scale Q for attention
    #pragma unroll
    for (int mi = 0; mi < 4; mi++) {
        #pragma unroll
        for (int ni = 0; ni < 4; ni++) {
            const int lcol = lc0 + ni * 16 + cl;
            const float bv = bias[lcol];
            #pragma unroll
            for (int r = 0; r < 4; r++) {
                const int row = m0 + wm * 64 + mi * 16 + gl * 4 + r;
                const float v = (acc[mi][ni][r] + bv) * scl;
                if (mode == 0) {
                    outp[(long)row * 1024 + lcol] = (bf16)v;
                } else if (mode == 1) {
                    outp[((long)(row >> 11) * 1024 + lcol) * T_ + (row & 2047)] = (bf16)v;
                } else {
                    outp[(long)row * 1024 + lcol] = (bf16)(1.0f / (1.0f + __expf(-v)));
                }
            }
        }
    }
}

// ---- W1: gelu -> bf16 h1. grid 256 x 512 thr (8-phase) ----
__global__ __launch_bounds__(512, 2) void gemmG8_k(const bf16* __restrict__ A, const bf16* __restrict__ Bt,
        const float* __restrict__ bias, bf16* __restrict__ out) {
    __shared__ __align__(16) char lds[131072];
    int bid = blockIdx.x;
    bid = (bid & 7) * 32 + (bid >> 3);
    const int m0 = (bid >> 4) * 256, n0 = (bid & 15) * 256;
    f32x4 acc[8][4];
    #pragma unroll
    for (int i = 0; i < 8; i++)
        #pragma unroll
        for (int j = 0; j < 4; j++) acc[i][j] = (f32x4){0.f, 0.f, 0.f, 0.f};
    gemm256_core(A, Bt, 1024, 16, m0, n0, lds, acc);
    const int tid = threadIdx.x, lane = tid & 63, w = tid >> 6;
    const int wm = w >> 2, wn = w & 3, cl = lane & 15, gl = lane >> 4;
    #pragma unroll
    for (int mi = 0; mi < 8; mi++) {
        #pragma unroll
        for (int ni = 0; ni < 4; ni++) {
            const int col = n0 + wn * 64 + ni * 16 + cl;
            const float bv = bias[col];
            #pragma unroll
            for (int r = 0; r < 4; r++) {
                const int row = m0 + wm * 128 + mi * 16 + gl * 4 + r;
                float v = acc[mi][ni][r] + bv;
                v = 0.5f * v * (1.0f + erff(v * 0.70710678118f));
                out[(long)row * DF_ + col] = (bf16)v;
            }
        }
    }
}

// ---- W2 split-K=4 -> 4 bf16 partials. grid 256 x 512 thr (8-phase) ----
__global__ __launch_bounds__(512, 2) void gemmP8_k(const bf16* __restrict__ A, const bf16* __restrict__ Bt,
        bf16* __restrict__ p0, bf16* __restrict__ p1, bf16* __restrict__ p2, bf16* __restrict__ p3) {
    __shared__ __align__(16) char lds[131072];
    int bid = blockIdx.x;
    bid = (bid & 7) * 32 + (bid >> 3);
    const int mt = bid >> 4, rest = bid & 15;
    const int nt = rest >> 2, s = rest & 3;
    const int m0 = mt * 256, n0 = nt * 256;
    f32x4 acc[8][4];
    #pragma unroll
    for (int i = 0; i < 8; i++)
        #pragma unroll
        for (int j = 0; j < 4; j++) acc[i][j] = (f32x4){0.f, 0.f, 0.f, 0.f};
    gemm256_core(A + s * 1024, Bt + s * 1024, 4096, 16, m0, n0, lds, acc);
    bf16* outp = (s == 0) ? p0 : (s == 1) ? p1 : (s == 2) ? p2 : p3;
    const int tid = threadIdx.x, lane = tid & 63, w = tid >> 6;
    const int wm = w >> 2, wn = w & 3, cl = lane & 15, gl = lane >> 4;
    #pragma unroll
    for (int mi = 0; mi < 8; mi++) {
        #pragma unroll
        for (int ni = 0; ni < 4; ni++) {
            const int col = n0 + wn * 64 + ni * 16 + cl;
            #pragma unroll
            for (int r = 0; r < 4; r++) {
                const int row = m0 + wm * 128 + mi * 16 + gl * 4 + r;
                outp[(long)row * 1024 + col] = (bf16)acc[mi][ni][r];
            }
        }
    }
}

// ---- Wo GEMM (128x128 4-wave core) with fused gate1 epilogue. grid 256 x 256 thr ----
__global__ __launch_bounds__(256, 4) void gemmWoG_kernel(const bf16* __restrict__ A,
        const bf16* __restrict__ Bt, const float* __restrict__ bias,
        float* __restrict__ x, const bf16* __restrict__ z, const bf16* __restrict__ rr) {
    __shared__ __align__(16) char lds[32768];
    int bid = blockIdx.x;
    bid = (bid & 7) * 32 + (bid >> 3);            // 256 blocks, bijective
    const int m0 = (bid >> 3) * 128, n0 = (bid & 7) * 128;
    f32x4 acc[4][4];
    #pragma unroll
    for (int i = 0; i < 4; i++)
        #pragma unroll
        for (int j = 0; j < 4; j++) acc[i][j] = (f32x4){0.f, 0.f, 0.f, 0.f};
    gemm64_core(A, Bt, 1024, 32, m0, n0, lds, acc);
    const int tid = threadIdx.x, lane = tid & 63, w = tid >> 6;
    const int wm = w >> 1, wn = w & 1, cl = lane & 15, gl = lane >> 4;
    #pragma unroll
    for (int mi = 0; mi < 4; mi++) {
        #pragma unroll
        for (int ni = 0; ni < 4; ni++) {
            const int col = n0 + wn * 64 + ni * 16 + cl;
            const float bv = bias[col];
            #pragma unroll
            for (int r = 0; r < 4; r++) {
                const int row = m0 + wm * 64 + mi * 16 + gl * 4 + r;
                const long idx = (long)row * D_ + col;
                const float xa = acc[mi][ni][r] + bv;
                const float zv = (float)z[idx];
                const float ht = tanhf((float)rr[idx] * xa);
                x[idx] = (1.f - zv) * x[idx] + zv * ht;
            }
        }
    }
}

// ======= Flash attention v2 (unchanged) =======
__global__ __launch_bounds__(256, 2) void attn_kernel(const bf16* __restrict__ q,
        const bf16* __restrict__ k, const bf16* __restrict__ vT,
        bf16* __restrict__ y) {
    __shared__ __align__(16) char lds[32768];
    const int tid = threadIdx.x, wid = tid >> 6, lane = tid & 63;
    const int col = lane & 31, hi = lane >> 5;
    const int bid = blockIdx.x;
    const int xcd = bid & 7, idx = bid >> 3;
    const int bh = xcd + 8 * (idx & 3);
    const int sg = idx >> 2;
    const int g = (sg & 1) ? (sg >> 1) : (15 - (sg >> 1));
    const int qt = 4 * g + wid;
    const int qb = qt * 32;
    const int b = bh >> 4, h = bh & 15;
    const int NP = 2 * g + 2;
    const int nt64 = (qt >> 1) + 1;

    const bf16* qB = q  + (size_t)b * T_ * D_ + h * HD_;
    const bf16* kB = k  + (size_t)b * T_ * D_ + h * HD_;
    const bf16* vB = vT + (size_t)b * D_ * T_ + (size_t)h * HD_ * T_;

    const int sr = wid * 8 + (lane >> 3);
    const int sc = lane & 7;
    const bf16* kS0 = kB + (size_t)sr * D_ + 8 * (sc ^ (sr & 7));
    const bf16* kS1 = kS0 + (size_t)32 * D_;
    const bf16* vS0 = vB + (size_t)sr * T_ + 8 * (sc ^ (sr & 7));
    const bf16* vS1 = vS0 + (size_t)32 * T_;
    char* dK = lds + wid * 1024;
    char* dV = lds + 16384 + wid * 1024;

#define ASTG(J, BUF) do { \
    const size_t ko_ = (size_t)(J) * 64 * D_; \
    const size_t vo_ = (size_t)(J) * 64; \
    gload_lds16(kS0 + ko_, dK + (BUF) * 8192); \
    gload_lds16(kS1 + ko_, dK + (BUF) * 8192 + 4096); \
    gload_lds16(vS0 + vo_, dV + (BUF) * 8192); \
    gload_lds16(vS1 + vo_, dV + (BUF) * 8192 + 4096); } while (0)

    bf16x8 qf0, qf1, qf2, qf3;
    {
        const bf16* qp = qB + (size_t)(qb + col) * D_ + 8 * hi;
        qf0 = *(const bf16x8*)(qp);
        qf1 = *(const bf16x8*)(qp + 16);
        qf2 = *(const bf16x8*)(qp + 32);
        qf3 = *(const bf16x8*)(qp + 48);
    }

    f32x16 Od0, Od1;
    #pragma unroll
    for (int i = 0; i < 16; i++) { Od0[i] = 0.f; Od1[i] = 0.f; }
    float mrun = -INFINITY, lrun = 0.f;

    ASTG(0, 0);
    ASTG(1, 1);
    VMC(4);
    BAR();

    const int swz = col & 7;
    for (int j = 0; j < NP; ++j) {
        const int buf = j & 1;
        if (j < nt64) {
            const char* bK = lds + buf * 8192;
            const char* bV = lds + 16384 + buf * 8192;
            bf16x8 kf0[4], kf1[4], vf0[4], vf1[4];
            #pragma unroll
            for (int cs = 0; cs < 4; cs++) {
                const int ch = ((hi + 2 * cs) ^ swz) * 16;
                kf0[cs] = *(const bf16x8*)(bK + col * 128 + ch);
                kf1[cs] = *(const bf16x8*)(bK + (col + 32) * 128 + ch);
                vf0[cs] = *(const bf16x8*)(bV + col * 128 + ch);
                vf1[cs] = *(const bf16x8*)(bV + (col + 32) * 128 + ch);
            }
            f32x16 S0, S1;
            #pragma unroll
            for (int i = 0; i < 16; i++) { S0[i] = 0.f; S1[i] = 0.f; }
            S0 = MFMA32(kf0[0], qf0, S0); S0 = MFMA32(kf0[1], qf1, S0);
            S0 = MFMA32(kf0[2], qf2, S0); S0 = MFMA32(kf0[3], qf3, S0);
            S1 = MFMA32(kf1[0], qf0, S1); S1 = MFMA32(kf1[1], qf1, S1);
            S1 = MFMA32(kf1[2], qf2, S1); S1 = MFMA32(kf1[3], qf3, S1);
            float p[32];
            #pragma unroll
            for (int r = 0; r < 16; r++) { p[r] = S0[r]; p[16 + r] = S1[r]; }
            if (j == nt64 - 1) {
                const int qr = qb + col;
                #pragma unroll
                for (int r = 0; r < 32; r++) {
                    const int kvl = 64 * j + 32 * (r >> 4)
                                  + (r & 3) + 8 * ((r & 15) >> 2) + 4 * hi;
                    if (kvl > qr) p[r] = -3.0e38f;
                }
            }
            float tm = p[0];
            #pragma unroll
            for (int r = 1; r < 32; r++) tm = fmaxf(tm, p[r]);
            tm = fmaxf(tm, __shfl_xor(tm, 32));
            if (!__all(tm <= mrun + 8.f)) {
                const float mn = fmaxf(mrun, tm);
                const float al = __expf(mrun - mn);
                lrun *= al;
                #pragma unroll
                for (int i = 0; i < 16; i++) { Od0[i] *= al; Od1[i] *= al; }
                mrun = mn;
            }
            float ts = 0.f;
            #pragma unroll
            for (int r = 0; r < 32; r++) { p[r] = __expf(p[r] - mrun); ts += p[r]; }
            ts += __shfl_xor(ts, 32);
            lrun += ts;
            bf16x8 pbf[4];
            #pragma unroll
            for (int t = 0; t < 2; t++) {
                const unsigned pw0 = pk2(p[16*t+0],  p[16*t+1]),  pw1 = pk2(p[16*t+2],  p[16*t+3]);
                const unsigned pw2 = pk2(p[16*t+4],  p[16*t+5]),  pw3 = pk2(p[16*t+6],  p[16*t+7]);
                const unsigned pw4 = pk2(p[16*t+8],  p[16*t+9]),  pw5 = pk2(p[16*t+10], p[16*t+11]);
                const unsigned pw6 = pk2(p[16*t+12], p[16*t+13]), pw7 = pk2(p[16*t+14], p[16*t+15]);
                const unsigned px0 = __shfl_xor((int)pw0, 32), px1 = __shfl_xor((int)pw1, 32);
                const unsigned px2 = __shfl_xor((int)pw2, 32), px3 = __shfl_xor((int)pw3, 32);
                const unsigned px4 = __shfl_xor((int)pw4, 32), px5 = __shfl_xor((int)pw5, 32);
                const unsigned px6 = __shfl_xor((int)pw6, 32), px7 = __shfl_xor((int)pw7, 32);
                const u32x4 c0 = hi ? (u32x4){px2, px3, pw2, pw3} : (u32x4){pw0, pw1, px0, px1};
                const u32x4 c1 = hi ? (u32x4){px6, px7, pw6, pw7} : (u32x4){pw4, pw5, px4, px5};
                pbf[2*t]   = __builtin_bit_cast(bf16x8, c0);
                pbf[2*t+1] = __builtin_bit_cast(bf16x8, c1);
            }
            #pragma unroll
            for (int f = 0; f < 4; f++) {
                Od0 = MFMA32(vf0[f], pbf[f], Od0);
                Od1 = MFMA32(vf1[f], pbf[f], Od1);
            }
        }
        BAR();
        if (j + 2 < NP) { ASTG(j + 2, buf); VMC(4); }
        else            { VMC(0); }
        BAR();
    }

    const float inv = 1.0f / lrun;
    bf16* yr = y + (size_t)(b * T_ + qb + col) * D_ + h * HD_;
    #pragma unroll
    for (int rg = 0; rg < 4; rg++) {
        const int d0 = 8 * rg + 4 * hi;
        uint2 s0 = { pk2(Od0[4*rg] * inv, Od0[4*rg+1] * inv), pk2(Od0[4*rg+2] * inv, Od0[4*rg+3] * inv) };
        *(uint2*)(yr + d0) = s0;
        uint2 s1 = { pk2(Od1[4*rg] * inv, Od1[4*rg+1] * inv), pk2(Od1[4*rg+2] * inv, Od1[4*rg+3] * inv) };
        *(uint2*)(yr + 32 + d0) = s1;
    }
#undef ASTG
}

// ---------------- gate2 (4 bf16 partials, bf16 z) + optional fused ln1 ----------------
template<bool LN>
__global__ __launch_bounds__(256) void gate2ln_kernel(float* __restrict__ x,
        const bf16* __restrict__ z,
        const bf16* __restrict__ p0, const bf16* __restrict__ p1,
        const bf16* __restrict__ p2, const bf16* __restrict__ p3,
        const float* __restrict__ src, const float* __restrict__ b2,
        const float* __restrict__ lw, const float* __restrict__ lb,
        bf16* __restrict__ xn) {
    const int row = blockIdx.x, t = threadIdx.x;
    const long i = (long)row * D_ + t * 4;
    float4 xv = *(const float4*)(x + i);
    const float4 zv = ld4bf(z + i);
    const float4 a0 = ld4bf(p0 + i);
    const float4 a1 = ld4bf(p1 + i);
    const float4 a2 = ld4bf(p2 + i);
    const float4 a3 = ld4bf(p3 + i);
    const float4 sv = *(const float4*)(src + i);
    const float4 bb = *(const float4*)(b2 + t * 4);
    xv.x = (1.f - zv.x) * xv.x + zv.x * (a0.x + a1.x + a2.x + a3.x + bb.x) + sv.x;
    xv.y = (1.f - zv.y) * xv.y + zv.y * (a0.y + a1.y + a2.y + a3.y + bb.y) + sv.y;
    xv.z = (1.f - zv.z) * xv.z + zv.z * (a0.z + a1.z + a2.z + a3.z + bb.z) + sv.z;
    xv.w = (1.f - zv.w) * xv.w + zv.w * (a0.w + a1.w + a2.w + a3.w + bb.w) + sv.w;
    *(float4*)(x + i) = xv;
    if (LN) {
        float s  = xv.x + xv.y + xv.z + xv.w;
        float sq = xv.x*xv.x + xv.y*xv.y + xv.z*xv.z + xv.w*xv.w;
        #pragma unroll
        for (int m = 32; m; m >>= 1) { s += __shfl_xor(s, m); sq += __shfl_xor(sq, m); }
        __shared__ float red[8];
        const int wid = t >> 6, lid = t & 63;
        if (lid == 0) { red[wid] = s; red[wid + 4] = sq; }
        __syncthreads();
        s  = red[0] + red[1] + red[2] + red[3];
        sq = red[4] + red[5] + red[6] + red[7];
        const float mu   = s * (1.0f / D_);
        const float var  = sq * (1.0f / D_) - mu * mu;
        const float rstd = rsqrtf(var + 1e-5f);
        const float4 wv = *(const float4*)(lw + t * 4);
        const float4 bv = *(const float4*)(lb + t * 4);
        bf16* o = xn + i;
        o[0] = (bf16)((xv.x - mu) * rstd * wv.x + bv.x);
        o[1] = (bf16)((xv.y - mu) * rstd * wv.y + bv.y);
        o[2] = (bf16)((xv.z - mu) * rstd * wv.z + bv.z);
        o[3] = (bf16)((xv.w - mu) * rstd * wv.w + bv.w);
    }
}

extern "C" void kernel_launch(void* const* d_in, const int* in_sizes, int n_in,
                              void* d_out, int out_size, void* d_ws, size_t ws_size,
                              hipStream_t stream) {
    const float* seq   = (const float*)d_in[0];
    const float* Wq    = (const float*)d_in[1];  const float* bq = (const float*)d_in[2];
    const float* Wk    = (const float*)d_in[3];  const float* bk = (const float*)d_in[4];
    const float* Wv    = (const float*)d_in[5];  const float* bv = (const float*)d_in[6];
    const float* Wo    = (const float*)d_in[7];  const float* bo = (const float*)d_in[8];
    const float* Wz    = (const float*)d_in[9];  const float* bz = (const float*)d_in[10];
    const float* Wr    = (const float*)d_in[11]; const float* br = (const float*)d_in[12];
    const float* W1    = (const float*)d_in[13]; const float* b1 = (const float*)d_in[14];
    const float* W2    = (const float*)d_in[15]; const float* b2 = (const float*)d_in[16];
    const float* ln1w  = (const float*)d_in[17]; const float* ln1b = (const float*)d_in[18];
    const float* ln2w  = (const float*)d_in[19]; const float* ln2b = (const float*)d_in[20];
    const float* lnfw  = (const float*)d_in[21]; const float* lnfb = (const float*)d_in[22];

    char* ws = (char*)d_ws;
    float* x   = (float*)(ws);                       // 16 MB
    bf16*  z   = (bf16*)(ws + ((size_t)16 << 20));   // 8 MB
    bf16*  r   = (bf16*)(ws + ((size_t)32 << 20));   // 8 MB (W2 partial 1)
    bf16*  xa  = (bf16*)(ws + ((size_t)48 << 20));   // 8 MB (W2 partial 0)
    bf16*  xn  = (bf16*)(ws + ((size_t)64 << 20));   // 8 MB
    bf16*  qb_ = (bf16*)(ws + ((size_t)72 << 20));   // 8 MB
    bf16*  kb_ = (bf16*)(ws + ((size_t)80 << 20));   // 8 MB
    bf16*  vtb = (bf16*)(ws + ((size_t)88 << 20));   // 8 MB
    bf16*  yb  = (bf16*)(ws + ((size_t)96 << 20));   // 8 MB
    bf16*  h1  = (bf16*)(ws + ((size_t)104 << 20));  // 32 MB
    bf16*  wt  = (bf16*)(ws + ((size_t)136 << 20));  // 36 MB weight pool
    bf16*  pt2 = (bf16*)(ws + ((size_t)172 << 20));  // 8 MB (W2 partial 2)
    bf16*  pt3 = (bf16*)(ws + ((size_t)188 << 20));  // 8 MB (W2 partial 3)

    bf16* wto = wt + (5u << 20);
    bf16* wt1 = wt + (6u << 20);
    bf16* wt2 = wt + (10u << 20);

    for (int i = 0; i < NL_; i++) {
        const long dd = (long)i * D_ * D_;
        wconv_all<<<14336, 256, 0, stream>>>(Wq + dd, Wk + dd, Wv + dd, Wz + dd,
                                             Wr + dd, Wo + dd,
                                             W1 + (long)i * D_ * DF_,
                                             W2 + (long)i * DF_ * D_, wt);
        if (i == 0)
            ln_first_kernel<<<M_, 256, 0, stream>>>(seq, ln1w, ln1b, x, xn);
        gemm5_k<<<640, 512, 0, stream>>>(xn, wt,
                bq + i * D_, bk + i * D_, bv + i * D_, bz + i * D_, br + i * D_,
                qb_, kb_, vtb, z, r);
        attn_kernel<<<512, 256, 0, stream>>>(qb_, kb_, vtb, yb);
        gemmWoG_kernel<<<256, 256, 0, stream>>>(yb, wto, bo + i * D_, x, z, r);
        ln_kernel<true><<<M_, 256, 0, stream>>>(x, ln2w + i * D_, ln2b + i * D_, xn);
        gemmG8_k<<<256, 512, 0, stream>>>(xn, wt1, b1 + i * DF_, h1);
        gemmP8_k<<<256, 512, 0, stream>>>(h1, wt2, xa, r, pt2, pt3);
        if (i + 1 < NL_)
            gate2ln_kernel<true><<<M_, 256, 0, stream>>>(x, z, xa, r, pt2, pt3, seq, b2 + i * D_,
                    ln1w + (i + 1) * D_, ln1b + (i + 1) * D_, xn);
        else
            gate2ln_kernel<false><<<M_, 256, 0, stream>>>(x, z, xa, r, pt2, pt3, seq, b2 + i * D_,
                    nullptr, nullptr, nullptr);
    }
    ln_kernel<false><<<M_, 256, 0, stream>>>(x, lnfw, lnfb, d_out);
}